// Round 2
// baseline (813.138 us; speedup 1.0000x reference)
//
#include <hip/hip_runtime.h>

#define N_NODES 100000
#define N_EDGES 1600000
#define D 64

#define BIN_ROWS 128       // rows per bin
#define NBINS 782          // ceil(100000 / 128)
#define BIN_CAP 2560       // mean 2046, sigma ~45 -> +11 sigma
#define CHUNK 4096         // edges per pass-A block
#define NCHUNK ((N_EDGES + CHUNK - 1) / CHUNK)   // 391
#define APT (CHUNK / 512)  // 8 edges per thread in passA

__device__ __forceinline__ unsigned short f2bf(float f) {   // RNE float->bf16
    unsigned int u = __float_as_uint(f);
    u += 0x7FFFu + ((u >> 16) & 1u);
    return (unsigned short)(u >> 16);
}
__device__ __forceinline__ float bf2f(unsigned short u) {
    return __uint_as_float(((unsigned int)u) << 16);
}

// ---- pass A: multisplit edges into 782 bins of 128 rows, coalesced writes -
// record u64: lo32 = (w15<<17)|col ; hi32 = lrow(7b) | (bin<<7)
__global__ __launch_bounds__(512) void passA_k(const int* __restrict__ ei,
                                               const float* __restrict__ ew,
                                               int* __restrict__ bin_cursor,
                                               unsigned long long* __restrict__ binbuf) {
    __shared__ unsigned long long recs[CHUNK];   // 32 KB
    __shared__ int hist[NBINS], start[NBINS], gbase[NBINS];   // 9.4 KB
    __shared__ int ts[512];

    int t = threadIdx.x;
    int base = blockIdx.x * CHUNK;
    int cnt = N_EDGES - base; if (cnt > CHUNK) cnt = CHUNK;

    for (int i = t; i < NBINS; i += 512) hist[i] = 0;
    __syncthreads();

    unsigned long long rec[APT];
    int rbin[APT], rank[APT];
#pragma unroll
    for (int k = 0; k < APT; ++k) {
        int j = t + k * 512;
        rbin[k] = -1;
        if (j < cnt) {
            int e = base + j;
            int r = __builtin_nontemporal_load(&ei[e]);
            int c = __builtin_nontemporal_load(&ei[N_EDGES + e]);
            float w = __builtin_nontemporal_load(&ew[e]);
            unsigned int w15 = (unsigned int)__float2int_rn(w * 32767.0f);
            int bin = r >> 7;
            unsigned int lo = (w15 << 17) | (unsigned int)c;
            unsigned int hi = (unsigned int)(r & 127) | ((unsigned int)bin << 7);
            rec[k] = ((unsigned long long)hi << 32) | lo;
            rbin[k] = bin;
            rank[k] = atomicAdd(&hist[bin], 1);   // rank doubles as placement
        }
    }
    __syncthreads();

    // exclusive scan over 782 bins: 2 bins/thread + 512-wide Hillis-Steele
    int idx0 = 2 * t, idx1 = 2 * t + 1;
    int h0 = (idx0 < NBINS) ? hist[idx0] : 0;
    int h1 = (idx1 < NBINS) ? hist[idx1] : 0;
    int pair = h0 + h1;
    ts[t] = pair;
    __syncthreads();
    for (int off = 1; off < 512; off <<= 1) {
        int v = (t >= off) ? ts[t - off] : 0;
        __syncthreads();
        ts[t] += v;
        __syncthreads();
    }
    int pbase = ts[t] - pair;
    if (idx0 < NBINS) {
        start[idx0] = pbase;
        gbase[idx0] = (h0 > 0) ? atomicAdd(&bin_cursor[idx0], h0) : 0;
    }
    if (idx1 < NBINS) {
        start[idx1] = pbase + h0;
        gbase[idx1] = (h1 > 0) ? atomicAdd(&bin_cursor[idx1], h1) : 0;
    }
    __syncthreads();

    // place into LDS bin-sorted using rank (no second atomic)
#pragma unroll
    for (int k = 0; k < APT; ++k)
        if (rbin[k] >= 0)
            recs[start[rbin[k]] + rank[k]] = rec[k];
    __syncthreads();

    // coalesced copy-out (binbuf is re-read twice: keep cacheable)
    for (int j = t; j < cnt; j += 512) {
        unsigned long long r = recs[j];
        int bin = (int)(((unsigned int)(r >> 32)) >> 7);
        int gpos = gbase[bin] + (j - start[bin]);
        if (gpos < BIN_CAP)
            binbuf[(size_t)bin * BIN_CAP + gpos] = r;
    }
}

// ---- dinv: per-bin LDS weight sums from binbuf (no global atomics) -------
__global__ __launch_bounds__(256) void dinv_k(const int* __restrict__ bin_cursor,
                                              const unsigned long long* __restrict__ binbuf,
                                              float* __restrict__ dinv) {
    __shared__ unsigned int wsumL[BIN_ROWS];
    int b = blockIdx.x, t = threadIdx.x;
    int cnt = bin_cursor[b]; if (cnt > BIN_CAP) cnt = BIN_CAP;
    const unsigned long long* bb = binbuf + (size_t)b * BIN_CAP;
    if (t < BIN_ROWS) wsumL[t] = 0u;
    __syncthreads();
    for (int j = t; j < cnt; j += 256) {
        unsigned long long r = bb[j];
        atomicAdd(&wsumL[(unsigned int)(r >> 32) & 127u],
                  ((unsigned int)r) >> 17);
    }
    __syncthreads();
    if (t < BIN_ROWS) {
        int n = b * BIN_ROWS + t;
        if (n < N_NODES)
            dinv[n] = rsqrtf(1.0f + (float)wsumL[t] * (1.0f / 32767.0f));
    }
}

// ---------------------- y' = dinv .* (X * W^T), stored bf16 ---------------
__global__ __launch_bounds__(256) void xw_k(const float* __restrict__ x,
                                            const float* __restrict__ W,
                                            const float* __restrict__ dinv,
                                            unsigned short* __restrict__ yp) {
    __shared__ float xsT[64][68];   // [k][node]
    __shared__ float Wt[64][68];    // [k][feat]
    int tid = threadIdx.x;
    int nbase = blockIdx.x * 64;
#pragma unroll
    for (int r = 0; r < 4; ++r) {   // W: [j][k] row-major, 4096 floats
        int idx = r * 1024 + tid * 4;
        int j = idx >> 6, k = idx & 63;
        float4 v = *(const float4*)(W + idx);
        Wt[k + 0][j] = v.x; Wt[k + 1][j] = v.y; Wt[k + 2][j] = v.z; Wt[k + 3][j] = v.w;
    }
#pragma unroll
    for (int r = 0; r < 4; ++r) {   // x block, transposed into LDS
        int idx = r * 1024 + tid * 4;
        int nl = idx >> 6, k = idx & 63;
        int n = nbase + nl;
        float4 v = (n < N_NODES) ? *(const float4*)(x + n * 64 + k)
                                 : make_float4(0.f, 0.f, 0.f, 0.f);
        xsT[k + 0][nl] = v.x; xsT[k + 1][nl] = v.y; xsT[k + 2][nl] = v.z; xsT[k + 3][nl] = v.w;
    }
    __syncthreads();

    int tx = tid & 15;          // feature group: j0 = tx*4
    int ty = tid >> 4;          // node group:    n0 = ty*4
    float acc[4][4];
#pragma unroll
    for (int i = 0; i < 4; ++i)
#pragma unroll
        for (int j = 0; j < 4; ++j) acc[i][j] = 0.f;

#pragma unroll 8
    for (int k = 0; k < 64; ++k) {
        float4 a = *(const float4*)&xsT[k][ty * 4];
        float4 w = *(const float4*)&Wt[k][tx * 4];
        float av[4] = {a.x, a.y, a.z, a.w};
        float wv[4] = {w.x, w.y, w.z, w.w};
#pragma unroll
        for (int i = 0; i < 4; ++i)
#pragma unroll
            for (int j = 0; j < 4; ++j) acc[i][j] += av[i] * wv[j];
    }
#pragma unroll
    for (int i = 0; i < 4; ++i) {
        int n = nbase + ty * 4 + i;
        if (n < N_NODES) {
            float di = dinv[n];
            ushort4 v;
            v.x = f2bf(di * acc[i][0]);
            v.y = f2bf(di * acc[i][1]);
            v.z = f2bf(di * acc[i][2]);
            v.w = f2bf(di * acc[i][3]);
            *(ushort4*)(yp + n * 64 + tx * 4) = v;   // 8B store
        }
    }
}

// ---- fused sort-free gather: 1 block per bin; LDS float accumulation -----
// acc[lrow][lane] += w15 * y'[col][lane]; epilogue adds self + bias.
// Replaces passB + base_k + csr + row_ptr + gather_k.
__global__ __launch_bounds__(256) void bingather_k(const int* __restrict__ bin_cursor,
                                                   const unsigned long long* __restrict__ binbuf,
                                                   const float* __restrict__ dinv,
                                                   const unsigned short* __restrict__ yp,
                                                   const float* __restrict__ b,
                                                   float* __restrict__ out) {
    __shared__ float acc[BIN_ROWS][D];   // 32 KB
    int t = threadIdx.x;
    int wv = t >> 6, lane = t & 63;
    int bin = blockIdx.x;
    int cnt = bin_cursor[bin]; if (cnt > BIN_CAP) cnt = BIN_CAP;
    const unsigned long long* bb = binbuf + (size_t)bin * BIN_CAP;

    // zero accumulator (float4-wide)
    for (int i = t; i < BIN_ROWS * D / 4; i += 256)
        ((float4*)acc)[i] = make_float4(0.f, 0.f, 0.f, 0.f);
    __syncthreads();

    // each wave independently walks the bin's records, 64 at a time
    for (int base0 = wv * 64; base0 < cnt; base0 += 256) {
        int m = cnt - base0; if (m > 64) m = 64;
        unsigned int lo_r = 0u, hi_r = 0u;
        if (lane < m) {
            unsigned long long rec = bb[base0 + lane];   // coalesced 512B/wave
            lo_r = (unsigned int)rec;
            hi_r = (unsigned int)(rec >> 32);
        }
        int r = 0;
        for (; r + 7 < m; r += 8) {
            unsigned int lo[8], hi[8];
#pragma unroll
            for (int q = 0; q < 8; ++q) {
                lo[q] = __builtin_amdgcn_readlane(lo_r, r + q);
                hi[q] = __builtin_amdgcn_readlane(hi_r, r + q);
            }
            float yv[8];
#pragma unroll
            for (int q = 0; q < 8; ++q)
                yv[q] = bf2f(yp[(lo[q] & 0x1FFFFu) * D + lane]);
#pragma unroll
            for (int q = 0; q < 8; ++q)
                atomicAdd(&acc[hi[q] & 127u][lane],
                          (float)(lo[q] >> 17) * yv[q]);
        }
        for (; r < m; ++r) {
            unsigned int lo = __builtin_amdgcn_readlane(lo_r, r);
            unsigned int hi = __builtin_amdgcn_readlane(hi_r, r);
            atomicAdd(&acc[hi & 127u][lane],
                      (float)(lo >> 17) * bf2f(yp[(lo & 0x1FFFFu) * D + lane]));
        }
    }
    __syncthreads();

    // epilogue: out = dinv*(self + acc/32767) + b ; coalesced 256B stores
    for (int lr = wv; lr < BIN_ROWS; lr += 4) {
        int n = bin * BIN_ROWS + lr;
        if (n < N_NODES) {
            float di = dinv[n];
            float self = bf2f(yp[n * D + lane]);
            float o = di * (self + acc[lr][lane] * (1.0f / 32767.0f)) + b[lane];
            __builtin_nontemporal_store(o, &out[n * D + lane]);
        }
    }
}

// ---------------------------------------------------------------------------
extern "C" void kernel_launch(void* const* d_in, const int* in_sizes, int n_in,
                              void* d_out, int out_size, void* d_ws, size_t ws_size,
                              hipStream_t stream) {
    const float* x  = (const float*)d_in[0];
    const int*   ei = (const int*)d_in[1];     // [2, E]
    const float* ew = (const float*)d_in[2];
    const float* W  = (const float*)d_in[3];
    const float* b  = (const float*)d_in[4];
    float* out = (float*)d_out;

    char* ws = (char*)d_ws;
    int*                bin_cursor = (int*)                ws;               // 3.1 KB
    float*              dinv       = (float*)             (ws + 0x10000);    // 400 KB
    unsigned short*     yp         = (unsigned short*)    (ws + 0x80000);    // 12.8 MB
    unsigned long long* binbuf     = (unsigned long long*)(ws + 0xD00000);   // 16.0 MB (end ~29.6 MB)

    hipMemsetAsync(bin_cursor, 0, NBINS * sizeof(int), stream);
    passA_k    <<<NCHUNK, 512, 0, stream>>>(ei, ew, bin_cursor, binbuf);
    dinv_k     <<<NBINS, 256, 0, stream>>>(bin_cursor, binbuf, dinv);
    xw_k       <<<(N_NODES + 63) / 64, 256, 0, stream>>>(x, W, dinv, yp);
    bingather_k<<<NBINS, 256, 0, stream>>>(bin_cursor, binbuf, dinv, yp, b, out);
}

// Round 3
// 720.495 us; speedup vs baseline: 1.1286x; 1.1286x over previous
//
#include <hip/hip_runtime.h>

#define N_NODES 100000
#define N_EDGES 1600000
#define D 64

#define BIN_ROWS 32        // rows per bin
#define NBINS 3125         // 100000 / 32 exactly
#define BIN_CAP 768        // mean 512, sigma ~22.6 -> +11 sigma
#define CHUNK 4096         // edges per pass-A block
#define NCHUNK ((N_EDGES + CHUNK - 1) / CHUNK)   // 391
#define APT (CHUNK / 512)  // 8 edges per thread in passA
#define BPT 7              // bins per thread in passA scan (512*7 >= 3125)

__device__ __forceinline__ unsigned short f2bf(float f) {   // RNE float->bf16
    unsigned int u = __float_as_uint(f);
    u += 0x7FFFu + ((u >> 16) & 1u);
    return (unsigned short)(u >> 16);
}
__device__ __forceinline__ float bf2f(unsigned short u) {
    return __uint_as_float(((unsigned int)u) << 16);
}

// ---- pass A: multisplit edges into 3125 bins of 32 rows, coalesced writes -
// record u64: lo32 = (w15<<17)|col ; hi32 = lrow(5b) | (bin<<5)
__global__ __launch_bounds__(512) void passA_k(const int* __restrict__ ei,
                                               const float* __restrict__ ew,
                                               int* __restrict__ bin_cursor,
                                               unsigned long long* __restrict__ binbuf) {
    __shared__ unsigned long long recs[CHUNK];   // 32 KB
    __shared__ int hs[NBINS];                    // hist, then start (12.5 KB)
    __shared__ int gbase[NBINS];                 // 12.5 KB
    __shared__ int ts[512];                      // 2 KB   (total ~59 KB)

    int t = threadIdx.x;
    int base = blockIdx.x * CHUNK;
    int cnt = N_EDGES - base; if (cnt > CHUNK) cnt = CHUNK;

    for (int i = t; i < NBINS; i += 512) hs[i] = 0;
    __syncthreads();

    unsigned long long rec[APT];
    int rbin[APT], rank[APT];
#pragma unroll
    for (int k = 0; k < APT; ++k) {
        int j = t + k * 512;
        rbin[k] = -1;
        if (j < cnt) {
            int e = base + j;
            int r = __builtin_nontemporal_load(&ei[e]);
            int c = __builtin_nontemporal_load(&ei[N_EDGES + e]);
            float w = __builtin_nontemporal_load(&ew[e]);
            unsigned int w15 = (unsigned int)__float2int_rn(w * 32767.0f);
            int bin = r >> 5;
            unsigned int lo = (w15 << 17) | (unsigned int)c;
            unsigned int hi = (unsigned int)(r & 31) | ((unsigned int)bin << 5);
            rec[k] = ((unsigned long long)hi << 32) | lo;
            rbin[k] = bin;
            rank[k] = atomicAdd(&hs[bin], 1);   // rank doubles as placement
        }
    }
    __syncthreads();

    // exclusive scan over 3125 bins: 7 bins/thread + 512-wide Hillis-Steele
    int h[BPT]; int local = 0;
#pragma unroll
    for (int q = 0; q < BPT; ++q) {
        int idx = t * BPT + q;
        h[q] = (idx < NBINS) ? hs[idx] : 0;
        local += h[q];
    }
    ts[t] = local;
    __syncthreads();
    for (int off = 1; off < 512; off <<= 1) {
        int v = (t >= off) ? ts[t - off] : 0;
        __syncthreads();
        ts[t] += v;
        __syncthreads();
    }
    int run = ts[t] - local;
#pragma unroll
    for (int q = 0; q < BPT; ++q) {
        int idx = t * BPT + q;
        if (idx < NBINS) {
            hs[idx] = run;                       // hs now holds chunk-local start
            gbase[idx] = (h[q] > 0) ? atomicAdd(&bin_cursor[idx], h[q]) : 0;
            run += h[q];
        }
    }
    __syncthreads();

    // place into LDS bin-sorted using rank (no second atomic)
#pragma unroll
    for (int k = 0; k < APT; ++k)
        if (rbin[k] >= 0)
            recs[hs[rbin[k]] + rank[k]] = rec[k];
    __syncthreads();

    // coalesced copy-out (binbuf is re-read twice: keep cacheable)
    for (int j = t; j < cnt; j += 512) {
        unsigned long long r = recs[j];
        int bin = (int)(((unsigned int)(r >> 32)) >> 5);
        int gpos = gbase[bin] + (j - hs[bin]);
        if (gpos < BIN_CAP)
            binbuf[(size_t)bin * BIN_CAP + gpos] = r;
    }
}

// ---- dinv: per-bin LDS weight sums from binbuf (no global atomics) -------
__global__ __launch_bounds__(256) void dinv_k(const int* __restrict__ bin_cursor,
                                              const unsigned long long* __restrict__ binbuf,
                                              float* __restrict__ dinv) {
    __shared__ unsigned int wsumL[BIN_ROWS];
    int b = blockIdx.x, t = threadIdx.x;
    int cnt = bin_cursor[b]; if (cnt > BIN_CAP) cnt = BIN_CAP;
    const unsigned long long* bb = binbuf + (size_t)b * BIN_CAP;
    if (t < BIN_ROWS) wsumL[t] = 0u;
    __syncthreads();
    for (int j = t; j < cnt; j += 256) {
        unsigned long long r = bb[j];
        atomicAdd(&wsumL[(unsigned int)(r >> 32) & 31u],
                  ((unsigned int)r) >> 17);
    }
    __syncthreads();
    if (t < BIN_ROWS) {
        int n = b * BIN_ROWS + t;
        dinv[n] = rsqrtf(1.0f + (float)wsumL[t] * (1.0f / 32767.0f));
    }
}

// ---------------------- y' = dinv .* (X * W^T), stored bf16 ---------------
__global__ __launch_bounds__(256) void xw_k(const float* __restrict__ x,
                                            const float* __restrict__ W,
                                            const float* __restrict__ dinv,
                                            unsigned short* __restrict__ yp) {
    __shared__ float xsT[64][68];   // [k][node]
    __shared__ float Wt[64][68];    // [k][feat]
    int tid = threadIdx.x;
    int nbase = blockIdx.x * 64;
#pragma unroll
    for (int r = 0; r < 4; ++r) {   // W: [j][k] row-major, 4096 floats
        int idx = r * 1024 + tid * 4;
        int j = idx >> 6, k = idx & 63;
        float4 v = *(const float4*)(W + idx);
        Wt[k + 0][j] = v.x; Wt[k + 1][j] = v.y; Wt[k + 2][j] = v.z; Wt[k + 3][j] = v.w;
    }
#pragma unroll
    for (int r = 0; r < 4; ++r) {   // x block, transposed into LDS
        int idx = r * 1024 + tid * 4;
        int nl = idx >> 6, k = idx & 63;
        int n = nbase + nl;
        float4 v = (n < N_NODES) ? *(const float4*)(x + n * 64 + k)
                                 : make_float4(0.f, 0.f, 0.f, 0.f);
        xsT[k + 0][nl] = v.x; xsT[k + 1][nl] = v.y; xsT[k + 2][nl] = v.z; xsT[k + 3][nl] = v.w;
    }
    __syncthreads();

    int tx = tid & 15;          // feature group: j0 = tx*4
    int ty = tid >> 4;          // node group:    n0 = ty*4
    float acc[4][4];
#pragma unroll
    for (int i = 0; i < 4; ++i)
#pragma unroll
        for (int j = 0; j < 4; ++j) acc[i][j] = 0.f;

#pragma unroll 8
    for (int k = 0; k < 64; ++k) {
        float4 a = *(const float4*)&xsT[k][ty * 4];
        float4 w = *(const float4*)&Wt[k][tx * 4];
        float av[4] = {a.x, a.y, a.z, a.w};
        float wv[4] = {w.x, w.y, w.z, w.w};
#pragma unroll
        for (int i = 0; i < 4; ++i)
#pragma unroll
            for (int j = 0; j < 4; ++j) acc[i][j] += av[i] * wv[j];
    }
#pragma unroll
    for (int i = 0; i < 4; ++i) {
        int n = nbase + ty * 4 + i;
        if (n < N_NODES) {
            float di = dinv[n];
            ushort4 v;
            v.x = f2bf(di * acc[i][0]);
            v.y = f2bf(di * acc[i][1]);
            v.z = f2bf(di * acc[i][2]);
            v.w = f2bf(di * acc[i][3]);
            *(ushort4*)(yp + n * 64 + tx * 4) = v;   // 8B store
        }
    }
}

// ---- fused sort-free gather: 1 block per 32-row bin; LDS accumulation ----
// acc[lrow][lane] += w15 * y'[col][lane]; epilogue adds self + bias.
// 3125 blocks / 8 KB LDS -> high occupancy; short serial chains per wave.
__global__ __launch_bounds__(256) void bingather_k(const int* __restrict__ bin_cursor,
                                                   const unsigned long long* __restrict__ binbuf,
                                                   const float* __restrict__ dinv,
                                                   const unsigned short* __restrict__ yp,
                                                   const float* __restrict__ b,
                                                   float* __restrict__ out) {
    __shared__ float acc[BIN_ROWS][D];   // 8 KB
    int t = threadIdx.x;
    int wv = t >> 6, lane = t & 63;
    int bin = blockIdx.x;
    int cnt = bin_cursor[bin]; if (cnt > BIN_CAP) cnt = BIN_CAP;
    const unsigned long long* bb = binbuf + (size_t)bin * BIN_CAP;

    // zero accumulator (float4-wide)
    for (int i = t; i < BIN_ROWS * D / 4; i += 256)
        ((float4*)acc)[i] = make_float4(0.f, 0.f, 0.f, 0.f);
    __syncthreads();

    // each wave independently walks the bin's records, 64 at a time
    for (int base0 = wv * 64; base0 < cnt; base0 += 256) {
        int m = cnt - base0; if (m > 64) m = 64;
        unsigned int lo_r = 0u, hi_r = 0u;
        if (lane < m) {
            unsigned long long rec = bb[base0 + lane];   // coalesced 512B/wave
            lo_r = (unsigned int)rec;
            hi_r = (unsigned int)(rec >> 32);
        }
        int r = 0;
        for (; r + 7 < m; r += 8) {
            unsigned int lo[8], hi[8];
#pragma unroll
            for (int q = 0; q < 8; ++q) {
                lo[q] = __builtin_amdgcn_readlane(lo_r, r + q);
                hi[q] = __builtin_amdgcn_readlane(hi_r, r + q);
            }
            float yv[8];
#pragma unroll
            for (int q = 0; q < 8; ++q)
                yv[q] = bf2f(yp[(lo[q] & 0x1FFFFu) * D + lane]);
#pragma unroll
            for (int q = 0; q < 8; ++q)
                atomicAdd(&acc[hi[q] & 31u][lane],
                          (float)(lo[q] >> 17) * yv[q]);
        }
        for (; r < m; ++r) {
            unsigned int lo = __builtin_amdgcn_readlane(lo_r, r);
            unsigned int hi = __builtin_amdgcn_readlane(hi_r, r);
            atomicAdd(&acc[hi & 31u][lane],
                      (float)(lo >> 17) * bf2f(yp[(lo & 0x1FFFFu) * D + lane]));
        }
    }
    __syncthreads();

    // epilogue: out = dinv*(self + acc/32767) + b ; coalesced 256B stores
    for (int lr = wv; lr < BIN_ROWS; lr += 4) {
        int n = bin * BIN_ROWS + lr;      // always < N_NODES (3125*32 = 100000)
        float di = dinv[n];
        float self = bf2f(yp[n * D + lane]);
        float o = di * (self + acc[lr][lane] * (1.0f / 32767.0f)) + b[lane];
        __builtin_nontemporal_store(o, &out[n * D + lane]);
    }
}

// ---------------------------------------------------------------------------
extern "C" void kernel_launch(void* const* d_in, const int* in_sizes, int n_in,
                              void* d_out, int out_size, void* d_ws, size_t ws_size,
                              hipStream_t stream) {
    const float* x  = (const float*)d_in[0];
    const int*   ei = (const int*)d_in[1];     // [2, E]
    const float* ew = (const float*)d_in[2];
    const float* W  = (const float*)d_in[3];
    const float* b  = (const float*)d_in[4];
    float* out = (float*)d_out;

    char* ws = (char*)d_ws;
    int*                bin_cursor = (int*)                ws;               // 12.5 KB
    float*              dinv       = (float*)             (ws + 0x10000);    // 400 KB
    unsigned short*     yp         = (unsigned short*)    (ws + 0x80000);    // 12.8 MB
    unsigned long long* binbuf     = (unsigned long long*)(ws + 0xD00000);   // 19.2 MB (end ~32.8 MB)

    hipMemsetAsync(bin_cursor, 0, NBINS * sizeof(int), stream);
    passA_k    <<<NCHUNK, 512, 0, stream>>>(ei, ew, bin_cursor, binbuf);
    dinv_k     <<<NBINS, 256, 0, stream>>>(bin_cursor, binbuf, dinv);
    xw_k       <<<(N_NODES + 63) / 64, 256, 0, stream>>>(x, W, dinv, yp);
    bingather_k<<<NBINS, 256, 0, stream>>>(bin_cursor, binbuf, dinv, yp, b, out);
}

// Round 5
// 211.403 us; speedup vs baseline: 3.8464x; 3.4082x over previous
//
#include <hip/hip_runtime.h>

#define N_NODES 100000
#define N_EDGES 1600000
#define D 64

#define BIN_ROWS 128       // rows per bin
#define NBINS 782          // ceil(100000 / 128)
#define BIN_CAP 2560       // mean 2046, sigma ~45 -> +11 sigma
#define CHUNK 4096         // edges per pass-A block
#define NCHUNK ((N_EDGES + CHUNK - 1) / CHUNK)   // 391
#define APT (CHUNK / 512)  // 8 edges per thread in passA

__device__ __forceinline__ unsigned short f2bf(float f) {   // RNE float->bf16
    unsigned int u = __float_as_uint(f);
    u += 0x7FFFu + ((u >> 16) & 1u);
    return (unsigned short)(u >> 16);
}
__device__ __forceinline__ float bf2f(unsigned short u) {
    return __uint_as_float(((unsigned int)u) << 16);
}

// ---- pass A: multisplit edges into 782 bins of 128 rows, coalesced writes -
// record u64: lo32 = (w15<<17)|col ; hi32 = lrow(7b) | (bin<<7)
// (byte-identical to the verified 193us round-0 kernel)
__global__ __launch_bounds__(512) void passA_k(const int* __restrict__ ei,
                                               const float* __restrict__ ew,
                                               int* __restrict__ bin_cursor,
                                               unsigned long long* __restrict__ binbuf) {
    __shared__ unsigned long long recs[CHUNK];   // 32 KB
    __shared__ int hist[NBINS], start[NBINS], gbase[NBINS];   // 9.4 KB
    __shared__ int ts[512];

    int t = threadIdx.x;
    int base = blockIdx.x * CHUNK;
    int cnt = N_EDGES - base; if (cnt > CHUNK) cnt = CHUNK;

    for (int i = t; i < NBINS; i += 512) hist[i] = 0;
    __syncthreads();

    unsigned long long rec[APT];
    int rbin[APT], rank[APT];
#pragma unroll
    for (int k = 0; k < APT; ++k) {
        int j = t + k * 512;
        rbin[k] = -1;
        if (j < cnt) {
            int e = base + j;
            int r = __builtin_nontemporal_load(&ei[e]);
            int c = __builtin_nontemporal_load(&ei[N_EDGES + e]);
            float w = __builtin_nontemporal_load(&ew[e]);
            unsigned int w15 = (unsigned int)__float2int_rn(w * 32767.0f);
            int bin = r >> 7;
            unsigned int lo = (w15 << 17) | (unsigned int)c;
            unsigned int hi = (unsigned int)(r & 127) | ((unsigned int)bin << 7);
            rec[k] = ((unsigned long long)hi << 32) | lo;
            rbin[k] = bin;
            rank[k] = atomicAdd(&hist[bin], 1);   // rank doubles as placement
        }
    }
    __syncthreads();

    // exclusive scan over 782 bins: 2 bins/thread + 512-wide Hillis-Steele
    int idx0 = 2 * t, idx1 = 2 * t + 1;
    int h0 = (idx0 < NBINS) ? hist[idx0] : 0;
    int h1 = (idx1 < NBINS) ? hist[idx1] : 0;
    int pair = h0 + h1;
    ts[t] = pair;
    __syncthreads();
    for (int off = 1; off < 512; off <<= 1) {
        int v = (t >= off) ? ts[t - off] : 0;
        __syncthreads();
        ts[t] += v;
        __syncthreads();
    }
    int pbase = ts[t] - pair;
    if (idx0 < NBINS) {
        start[idx0] = pbase;
        gbase[idx0] = (h0 > 0) ? atomicAdd(&bin_cursor[idx0], h0) : 0;
    }
    if (idx1 < NBINS) {
        start[idx1] = pbase + h0;
        gbase[idx1] = (h1 > 0) ? atomicAdd(&bin_cursor[idx1], h1) : 0;
    }
    __syncthreads();

    // place into LDS bin-sorted using rank (no second atomic)
#pragma unroll
    for (int k = 0; k < APT; ++k)
        if (rbin[k] >= 0)
            recs[start[rbin[k]] + rank[k]] = rec[k];
    __syncthreads();

    // coalesced copy-out (binbuf is re-read twice: keep cacheable)
    for (int j = t; j < cnt; j += 512) {
        unsigned long long r = recs[j];
        int bin = (int)(((unsigned int)(r >> 32)) >> 7);
        int gpos = gbase[bin] + (j - start[bin]);
        if (gpos < BIN_CAP)
            binbuf[(size_t)bin * BIN_CAP + gpos] = r;
    }
}

// ---- dinv: per-bin INT LDS weight sums from binbuf (no global atomics) ---
__global__ __launch_bounds__(256) void dinvB_k(const int* __restrict__ bin_cursor,
                                               const unsigned long long* __restrict__ binbuf,
                                               float* __restrict__ dinv) {
    __shared__ unsigned int wsumL[BIN_ROWS];
    int b = blockIdx.x, t = threadIdx.x;
    int cnt = bin_cursor[b]; if (cnt > BIN_CAP) cnt = BIN_CAP;
    const unsigned long long* bb = binbuf + (size_t)b * BIN_CAP;
    if (t < BIN_ROWS) wsumL[t] = 0u;
    __syncthreads();
    for (int j = t; j < cnt; j += 256) {
        unsigned long long r = bb[j];
        atomicAdd(&wsumL[(unsigned int)(r >> 32) & 127u],
                  ((unsigned int)r) >> 17);
    }
    __syncthreads();
    if (t < BIN_ROWS) {
        int n = b * BIN_ROWS + t;
        if (n < N_NODES)
            dinv[n] = rsqrtf(1.0f + (float)wsumL[t] * (1.0f / 32767.0f));
    }
}

// ---------------------- y' = dinv .* (X * W^T), stored bf16 ---------------
__global__ __launch_bounds__(256) void xw_k(const float* __restrict__ x,
                                            const float* __restrict__ W,
                                            const float* __restrict__ dinv,
                                            unsigned short* __restrict__ yp) {
    __shared__ float xsT[64][68];   // [k][node]
    __shared__ float Wt[64][68];    // [k][feat]
    int tid = threadIdx.x;
    int nbase = blockIdx.x * 64;
#pragma unroll
    for (int r = 0; r < 4; ++r) {   // W: [j][k] row-major, 4096 floats
        int idx = r * 1024 + tid * 4;
        int j = idx >> 6, k = idx & 63;
        float4 v = *(const float4*)(W + idx);
        Wt[k + 0][j] = v.x; Wt[k + 1][j] = v.y; Wt[k + 2][j] = v.z; Wt[k + 3][j] = v.w;
    }
#pragma unroll
    for (int r = 0; r < 4; ++r) {   // x block, transposed into LDS
        int idx = r * 1024 + tid * 4;
        int nl = idx >> 6, k = idx & 63;
        int n = nbase + nl;
        float4 v = (n < N_NODES) ? *(const float4*)(x + n * 64 + k)
                                 : make_float4(0.f, 0.f, 0.f, 0.f);
        xsT[k + 0][nl] = v.x; xsT[k + 1][nl] = v.y; xsT[k + 2][nl] = v.z; xsT[k + 3][nl] = v.w;
    }
    __syncthreads();

    int tx = tid & 15;          // feature group: j0 = tx*4
    int ty = tid >> 4;          // node group:    n0 = ty*4
    float acc[4][4];
#pragma unroll
    for (int i = 0; i < 4; ++i)
#pragma unroll
        for (int j = 0; j < 4; ++j) acc[i][j] = 0.f;

#pragma unroll 8
    for (int k = 0; k < 64; ++k) {
        float4 a = *(const float4*)&xsT[k][ty * 4];
        float4 w = *(const float4*)&Wt[k][tx * 4];
        float av[4] = {a.x, a.y, a.z, a.w};
        float wv[4] = {w.x, w.y, w.z, w.w};
#pragma unroll
        for (int i = 0; i < 4; ++i)
#pragma unroll
            for (int j = 0; j < 4; ++j) acc[i][j] += av[i] * wv[j];
    }
#pragma unroll
    for (int i = 0; i < 4; ++i) {
        int n = nbase + ty * 4 + i;
        if (n < N_NODES) {
            float di = dinv[n];
            ushort4 v;
            v.x = f2bf(di * acc[i][0]);
            v.y = f2bf(di * acc[i][1]);
            v.z = f2bf(di * acc[i][2]);
            v.w = f2bf(di * acc[i][3]);
            *(ushort4*)(yp + n * 64 + tx * 4) = v;   // 8B store
        }
    }
}

// ---- pass C: row-sort in LDS (round-0 passB) + fused register gather -----
// No global csr/row_ptr: records stay in LDS; each wave owns 32 rows and
// accumulates in REGISTERS (LDS float atomics are banned - round-3 lesson).
__global__ __launch_bounds__(256) void passC_k(const int* __restrict__ bin_cursor,
                                               const unsigned long long* __restrict__ binbuf,
                                               const float* __restrict__ dinv,
                                               const unsigned short* __restrict__ yp,
                                               const float* __restrict__ bias,
                                               float* __restrict__ out) {
    __shared__ unsigned long long stage[BIN_CAP];   // 20 KB
    __shared__ unsigned int outbuf[BIN_CAP];        // 10 KB
    __shared__ int hist[BIN_ROWS], rcur[BIN_ROWS], rstart[BIN_ROWS];
    __shared__ int ts[256];

    int bN = blockIdx.x;
    int t = threadIdx.x;
    int cnt = bin_cursor[bN]; if (cnt > BIN_CAP) cnt = BIN_CAP;
    const unsigned long long* bb = binbuf + (size_t)bN * BIN_CAP;

    if (t < BIN_ROWS) hist[t] = 0;
    __syncthreads();

    // stage records in LDS + row histogram (int LDS atomics: cheap)
    for (int j = t; j < cnt; j += 256) {
        unsigned long long r = bb[j];
        stage[j] = r;
        atomicAdd(&hist[(unsigned int)(r >> 32) & 127u], 1);
    }
    __syncthreads();

    // exclusive scan of 128 row counts (threads 0..127)
    int own = (t < BIN_ROWS) ? hist[t] : 0;
    ts[t] = own;
    __syncthreads();
    for (int off = 1; off < BIN_ROWS; off <<= 1) {
        int v = (t >= off && t < BIN_ROWS) ? ts[t - off] : 0;
        __syncthreads();
        if (t < BIN_ROWS) ts[t] += v;
        __syncthreads();
    }
    if (t < BIN_ROWS) {
        int rs = ts[t] - own;
        rcur[t] = rs;
        rstart[t] = rs;
    }
    __syncthreads();

    // reorder row-sorted within LDS (4B records)
    for (int j = t; j < cnt; j += 256) {
        unsigned long long r = stage[j];
        int lrow = (int)((unsigned int)(r >> 32) & 127u);
        int p = atomicAdd(&rcur[lrow], 1);
        outbuf[p] = (unsigned int)r;    // (w15<<17)|col
    }
    __syncthreads();

    // fused gather: wave wv owns rows [wv*32, wv*32+32); register acc.
    int wv = t >> 6, lane = t & 63;
    float bl = bias[lane];
    for (int lr = wv * 32; lr < wv * 32 + 32; ++lr) {
        int n = bN * BIN_ROWS + lr;
        if (n >= N_NODES) break;
        int rs = rstart[lr];
        int re = rs + hist[lr];
        float self = bf2f(yp[n * D + lane]);
        float acc0 = 0.f, acc1 = 0.f;
        // 16-deep batches; sentinel-pad short batches (col=n, w15=0 -> no-op)
        for (int j = rs; j < re; j += 16) {
            unsigned int u[16];
#pragma unroll
            for (int q = 0; q < 16; ++q)
                u[q] = (j + q < re) ? outbuf[j + q] : (unsigned int)n;
            float yv[16];
#pragma unroll
            for (int q = 0; q < 16; ++q)
                yv[q] = bf2f(yp[(u[q] & 0x1FFFFu) * D + lane]);
#pragma unroll
            for (int q = 0; q < 16; ++q) {
                float wf = (float)(u[q] >> 17);
                if (q & 1) acc1 += wf * yv[q];
                else       acc0 += wf * yv[q];
            }
        }
        float o = dinv[n] * (self + (acc0 + acc1) * (1.0f / 32767.0f)) + bl;
        __builtin_nontemporal_store(o, &out[n * D + lane]);
    }
}

// ---------------------------------------------------------------------------
extern "C" void kernel_launch(void* const* d_in, const int* in_sizes, int n_in,
                              void* d_out, int out_size, void* d_ws, size_t ws_size,
                              hipStream_t stream) {
    const float* x  = (const float*)d_in[0];
    const int*   ei = (const int*)d_in[1];     // [2, E]
    const float* ew = (const float*)d_in[2];
    const float* W  = (const float*)d_in[3];
    const float* b  = (const float*)d_in[4];
    float* out = (float*)d_out;

    char* ws = (char*)d_ws;
    int*                bin_cursor = (int*)                ws;               // 3.1 KB
    float*              dinv       = (float*)             (ws + 0x10000);    // 400 KB
    unsigned short*     yp         = (unsigned short*)    (ws + 0x80000);    // 12.8 MB
    unsigned long long* binbuf     = (unsigned long long*)(ws + 0xD00000);   // 16.0 MB (end ~29.6 MB)

    hipMemsetAsync(bin_cursor, 0, NBINS * sizeof(int), stream);
    passA_k<<<NCHUNK, 512, 0, stream>>>(ei, ew, bin_cursor, binbuf);
    dinvB_k<<<NBINS, 256, 0, stream>>>(bin_cursor, binbuf, dinv);
    xw_k   <<<(N_NODES + 63) / 64, 256, 0, stream>>>(x, W, dinv, yp);
    passC_k<<<NBINS, 256, 0, stream>>>(bin_cursor, binbuf, dinv, yp, b, out);
}

// Round 6
// 204.694 us; speedup vs baseline: 3.9725x; 1.0328x over previous
//
#include <hip/hip_runtime.h>

#define N_NODES 100000
#define N_EDGES 1600000
#define D 64

#define BIN_ROWS 64        // rows per bin
#define NBINS 1563         // ceil(100000 / 64)
#define BIN_CAP 1408       // mean 1024, sigma ~32 -> +12 sigma
#define CHUNK 4096         // edges per pass-A block
#define NCHUNK ((N_EDGES + CHUNK - 1) / CHUNK)   // 391
#define APT (CHUNK / 512)  // 8 edges per thread in passA
#define BPT 4              // bins per thread in passA scan (512*4 >= 1563)

__device__ __forceinline__ unsigned short f2bf(float f) {   // RNE float->bf16
    unsigned int u = __float_as_uint(f);
    u += 0x7FFFu + ((u >> 16) & 1u);
    return (unsigned short)(u >> 16);
}
__device__ __forceinline__ float bf2f(unsigned short u) {
    return __uint_as_float(((unsigned int)u) << 16);
}

// ---- pass A: multisplit edges into 1563 bins of 64 rows, coalesced writes -
// LDS rec u64: lo32 = (w15<<17)|col ; hi32 = lrow(6b) | (bin<<6)
// global: split streams pay[4B] = lo32, lrow[1B]  (bin is implicit)
__global__ __launch_bounds__(512) void passA_k(const int* __restrict__ ei,
                                               const float* __restrict__ ew,
                                               int* __restrict__ bin_cursor,
                                               unsigned int* __restrict__ pay_g,
                                               unsigned char* __restrict__ lrow_g) {
    __shared__ unsigned long long recs[CHUNK];   // 32 KB
    __shared__ int hs[NBINS];                    // hist, then start (6.25 KB)
    __shared__ int gbase[NBINS];                 // 6.25 KB
    __shared__ int ts[512];                      // 2 KB

    int t = threadIdx.x;
    int base = blockIdx.x * CHUNK;
    int cnt = N_EDGES - base; if (cnt > CHUNK) cnt = CHUNK;

    for (int i = t; i < NBINS; i += 512) hs[i] = 0;
    __syncthreads();

    unsigned long long rec[APT];
    int rbin[APT], rank[APT];
#pragma unroll
    for (int k = 0; k < APT; ++k) {
        int j = t + k * 512;
        rbin[k] = -1;
        if (j < cnt) {
            int e = base + j;
            int r = __builtin_nontemporal_load(&ei[e]);
            int c = __builtin_nontemporal_load(&ei[N_EDGES + e]);
            float w = __builtin_nontemporal_load(&ew[e]);
            unsigned int w15 = (unsigned int)__float2int_rn(w * 32767.0f);
            int bin = r >> 6;
            unsigned int lo = (w15 << 17) | (unsigned int)c;
            unsigned int hi = (unsigned int)(r & 63) | ((unsigned int)bin << 6);
            rec[k] = ((unsigned long long)hi << 32) | lo;
            rbin[k] = bin;
            rank[k] = atomicAdd(&hs[bin], 1);   // rank doubles as placement
        }
    }
    __syncthreads();

    // exclusive scan over 1563 bins: 4 bins/thread + 512-wide Hillis-Steele
    int h[BPT]; int local = 0;
#pragma unroll
    for (int q = 0; q < BPT; ++q) {
        int idx = t * BPT + q;
        h[q] = (idx < NBINS) ? hs[idx] : 0;
        local += h[q];
    }
    ts[t] = local;
    __syncthreads();
    for (int off = 1; off < 512; off <<= 1) {
        int v = (t >= off) ? ts[t - off] : 0;
        __syncthreads();
        ts[t] += v;
        __syncthreads();
    }
    int run = ts[t] - local;
#pragma unroll
    for (int q = 0; q < BPT; ++q) {
        int idx = t * BPT + q;
        if (idx < NBINS) {
            hs[idx] = run;                       // hs now holds chunk-local start
            gbase[idx] = (h[q] > 0) ? atomicAdd(&bin_cursor[idx], h[q]) : 0;
            run += h[q];
        }
    }
    __syncthreads();

    // place into LDS bin-sorted using rank (no second atomic)
#pragma unroll
    for (int k = 0; k < APT; ++k)
        if (rbin[k] >= 0)
            recs[hs[rbin[k]] + rank[k]] = rec[k];
    __syncthreads();

    // coalesced copy-out into split streams
    for (int j = t; j < cnt; j += 512) {
        unsigned long long r = recs[j];
        unsigned int hi = (unsigned int)(r >> 32);
        int bin = (int)(hi >> 6);
        int gpos = gbase[bin] + (j - hs[bin]);
        if (gpos < BIN_CAP) {
            size_t o = (size_t)bin * BIN_CAP + gpos;
            pay_g[o] = (unsigned int)r;
            lrow_g[o] = (unsigned char)(hi & 63u);
        }
    }
}

// ---- fused dinv + XW: one block per 64-row bin ---------------------------
// phase 1: wsum over bin records (LDS int atomics) -> dinv (LDS + global)
// phase 2: y' = dinv .* (X W^T) for the same 64 nodes, stored bf16
__global__ __launch_bounds__(256) void dxw_k(const int* __restrict__ bin_cursor,
                                             const unsigned int* __restrict__ pay_g,
                                             const unsigned char* __restrict__ lrow_g,
                                             const float* __restrict__ x,
                                             const float* __restrict__ W,
                                             float* __restrict__ dinv,
                                             unsigned short* __restrict__ yp) {
    __shared__ float xsT[64][68];   // [k][node] 17.4 KB
    __shared__ float Wt[64][68];    // [k][feat] 17.4 KB
    __shared__ unsigned int wsumL[BIN_ROWS];
    __shared__ float dl[BIN_ROWS];
    int b = blockIdx.x, tid = threadIdx.x;
    int cnt = bin_cursor[b]; if (cnt > BIN_CAP) cnt = BIN_CAP;
    const unsigned int* pp = pay_g + (size_t)b * BIN_CAP;
    const unsigned char* lp = lrow_g + (size_t)b * BIN_CAP;

    if (tid < BIN_ROWS) wsumL[tid] = 0u;
    __syncthreads();
    for (int j = tid; j < cnt; j += 256)
        atomicAdd(&wsumL[lp[j]], pp[j] >> 17);
    __syncthreads();
    if (tid < BIN_ROWS) {
        int n = b * BIN_ROWS + tid;
        float dv = rsqrtf(1.0f + (float)wsumL[tid] * (1.0f / 32767.0f));
        dl[tid] = dv;
        if (n < N_NODES) dinv[n] = dv;
    }
    // dl visibility for the epilogue is ordered by the post-staging barrier

    int nbase = b * 64;
#pragma unroll
    for (int r = 0; r < 4; ++r) {   // W: [j][k] row-major, 4096 floats
        int idx = r * 1024 + tid * 4;
        int j = idx >> 6, k = idx & 63;
        float4 v = *(const float4*)(W + idx);
        Wt[k + 0][j] = v.x; Wt[k + 1][j] = v.y; Wt[k + 2][j] = v.z; Wt[k + 3][j] = v.w;
    }
#pragma unroll
    for (int r = 0; r < 4; ++r) {   // x block, transposed into LDS
        int idx = r * 1024 + tid * 4;
        int nl = idx >> 6, k = idx & 63;
        int n = nbase + nl;
        float4 v = (n < N_NODES) ? *(const float4*)(x + n * 64 + k)
                                 : make_float4(0.f, 0.f, 0.f, 0.f);
        xsT[k + 0][nl] = v.x; xsT[k + 1][nl] = v.y; xsT[k + 2][nl] = v.z; xsT[k + 3][nl] = v.w;
    }
    __syncthreads();

    int tx = tid & 15;          // feature group: j0 = tx*4
    int ty = tid >> 4;          // node group:    n0 = ty*4
    float acc[4][4];
#pragma unroll
    for (int i = 0; i < 4; ++i)
#pragma unroll
        for (int j = 0; j < 4; ++j) acc[i][j] = 0.f;

#pragma unroll 8
    for (int k = 0; k < 64; ++k) {
        float4 a = *(const float4*)&xsT[k][ty * 4];
        float4 w = *(const float4*)&Wt[k][tx * 4];
        float av[4] = {a.x, a.y, a.z, a.w};
        float wv[4] = {w.x, w.y, w.z, w.w};
#pragma unroll
        for (int i = 0; i < 4; ++i)
#pragma unroll
            for (int j = 0; j < 4; ++j) acc[i][j] += av[i] * wv[j];
    }
#pragma unroll
    for (int i = 0; i < 4; ++i) {
        int nl = ty * 4 + i;
        int n = nbase + nl;
        if (n < N_NODES) {
            float di = dl[nl];
            ushort4 v;
            v.x = f2bf(di * acc[i][0]);
            v.y = f2bf(di * acc[i][1]);
            v.z = f2bf(di * acc[i][2]);
            v.w = f2bf(di * acc[i][3]);
            *(ushort4*)(yp + n * 64 + tx * 4) = v;   // 8B store
        }
    }
}

// ---- pass C: LDS row-sort + fused register gather; 512 thr, 8 waves ------
// 13.5 KB LDS -> grid-limited occupancy (~24-32 waves/CU vs 12 before).
__global__ __launch_bounds__(512) void passC_k(const int* __restrict__ bin_cursor,
                                               const unsigned int* __restrict__ pay_g,
                                               const unsigned char* __restrict__ lrow_g,
                                               const float* __restrict__ dinv,
                                               const unsigned short* __restrict__ yp,
                                               const float* __restrict__ bias,
                                               float* __restrict__ out) {
    __shared__ unsigned int payL[BIN_CAP];      // 5.6 KB
    __shared__ unsigned char lrL[BIN_CAP];      // 1.4 KB
    __shared__ unsigned int outb[BIN_CAP];      // 5.6 KB
    __shared__ int hist[BIN_ROWS], rcur[BIN_ROWS], rstart[BIN_ROWS];
    __shared__ int ts[BIN_ROWS];
    __shared__ float dl[BIN_ROWS];

    int bN = blockIdx.x;
    int t = threadIdx.x;
    int cnt = bin_cursor[bN]; if (cnt > BIN_CAP) cnt = BIN_CAP;
    const unsigned int* pp = pay_g + (size_t)bN * BIN_CAP;
    const unsigned char* lp = lrow_g + (size_t)bN * BIN_CAP;

    if (t < BIN_ROWS) {
        hist[t] = 0;
        dl[t] = dinv[bN * BIN_ROWS + t];   // within 400KB alloc even past N_NODES
    }
    __syncthreads();

    // stage records in LDS + row histogram (int LDS atomics: cheap)
    for (int j = t; j < cnt; j += 512) {
        unsigned int p = pp[j];
        unsigned char l = lp[j];
        payL[j] = p; lrL[j] = l;
        atomicAdd(&hist[l], 1);
    }
    __syncthreads();

    // exclusive scan of 64 row counts (threads 0..63)
    int own = (t < BIN_ROWS) ? hist[t] : 0;
    if (t < BIN_ROWS) ts[t] = own;
    __syncthreads();
    for (int off = 1; off < BIN_ROWS; off <<= 1) {
        int v = (t >= off && t < BIN_ROWS) ? ts[t - off] : 0;
        __syncthreads();
        if (t < BIN_ROWS) ts[t] += v;
        __syncthreads();
    }
    if (t < BIN_ROWS) {
        int rs = ts[t] - own;
        rcur[t] = rs;
        rstart[t] = rs;
    }
    __syncthreads();

    // reorder row-sorted within LDS (4B records)
    for (int j = t; j < cnt; j += 512) {
        int p = atomicAdd(&rcur[lrL[j]], 1);
        outb[p] = payL[j];
    }
    __syncthreads();

    // fused gather: wave wv owns rows [wv*8, wv*8+8); register acc.
    int wv = t >> 6, lane = t & 63;
    float bl = bias[lane];
    for (int lr = wv * 8; lr < wv * 8 + 8; ++lr) {
        int n = bN * BIN_ROWS + lr;
        if (n >= N_NODES) break;
        int rs = rstart[lr];
        int re = rs + hist[lr];
        float self = bf2f(yp[n * D + lane]);
        float a0 = 0.f, a1 = 0.f;
        // 16-deep batches; sentinel-pad short batches (col=n, w15=0 -> no-op)
        for (int j = rs; j < re; j += 16) {
            unsigned int u[16];
#pragma unroll
            for (int q = 0; q < 16; ++q)
                u[q] = (j + q < re) ? outb[j + q] : (unsigned int)n;
            float yv[16];
#pragma unroll
            for (int q = 0; q < 16; ++q)
                yv[q] = bf2f(yp[(u[q] & 0x1FFFFu) * D + lane]);
#pragma unroll
            for (int q = 0; q < 16; ++q) {
                float wf = (float)(u[q] >> 17);
                if (q & 1) a1 += wf * yv[q];
                else       a0 += wf * yv[q];
            }
        }
        float o = dl[lr] * (self + (a0 + a1) * (1.0f / 32767.0f)) + bl;
        __builtin_nontemporal_store(o, &out[n * D + lane]);
    }
}

// ---------------------------------------------------------------------------
extern "C" void kernel_launch(void* const* d_in, const int* in_sizes, int n_in,
                              void* d_out, int out_size, void* d_ws, size_t ws_size,
                              hipStream_t stream) {
    const float* x  = (const float*)d_in[0];
    const int*   ei = (const int*)d_in[1];     // [2, E]
    const float* ew = (const float*)d_in[2];
    const float* W  = (const float*)d_in[3];
    const float* b  = (const float*)d_in[4];
    float* out = (float*)d_out;

    char* ws = (char*)d_ws;
    int*            bin_cursor = (int*)            ws;                 // 6.25 KB
    float*          dinv       = (float*)         (ws + 0x10000);      // 400 KB
    unsigned short* yp         = (unsigned short*)(ws + 0x80000);      // 12.8 MB
    unsigned int*   pay_g      = (unsigned int*)  (ws + 0xD00000);     // 8.8 MB
    unsigned char*  lrow_g     = (unsigned char*) (ws + 0x1600000);    // 2.2 MB (end ~24.4 MB)

    hipMemsetAsync(bin_cursor, 0, NBINS * sizeof(int), stream);
    passA_k<<<NCHUNK, 512, 0, stream>>>(ei, ew, bin_cursor, pay_g, lrow_g);
    dxw_k  <<<NBINS, 256, 0, stream>>>(bin_cursor, pay_g, lrow_g, x, W, dinv, yp);
    passC_k<<<NBINS, 512, 0, stream>>>(bin_cursor, pay_g, lrow_g, dinv, yp, b, out);
}

// Round 7
// 197.686 us; speedup vs baseline: 4.1133x; 1.0354x over previous
//
#include <hip/hip_runtime.h>

#define N_NODES 100000
#define N_EDGES 1600000
#define D 64

#define BIN_ROWS 64        // rows per bin
#define NBINS 1563         // ceil(100000 / 64)
#define BIN_CAP 1408       // mean 1024, sigma ~32 -> +12 sigma
#define CHUNK 4096         // edges per pass-A block
#define NCHUNK ((N_EDGES + CHUNK - 1) / CHUNK)   // 391
#define APT (CHUNK / 512)  // 8 edges per thread in passA
#define BPT 4              // bins per thread in passA scan (512*4 >= 1563)
#define CSTRIDE 16         // one cursor per 64B line: kills cross-XCD
                           // same-line atomic serialization (round-6 lesson)

__device__ __forceinline__ unsigned short f2bf(float f) {   // RNE float->bf16
    unsigned int u = __float_as_uint(f);
    u += 0x7FFFu + ((u >> 16) & 1u);
    return (unsigned short)(u >> 16);
}
__device__ __forceinline__ float bf2f(unsigned short u) {
    return __uint_as_float(((unsigned int)u) << 16);
}

// ---- pass A: multisplit edges into 1563 bins of 64 rows, coalesced writes -
// LDS rec u64: lo32 = (w15<<17)|col ; hi32 = lrow(6b) | (bin<<6)
// global: split streams pay[4B] = lo32, lrow[1B]  (bin is implicit)
__global__ __launch_bounds__(512) void passA_k(const int* __restrict__ ei,
                                               const float* __restrict__ ew,
                                               int* __restrict__ bin_cursor,
                                               unsigned int* __restrict__ pay_g,
                                               unsigned char* __restrict__ lrow_g) {
    __shared__ unsigned long long recs[CHUNK];   // 32 KB
    __shared__ int hs[NBINS];                    // hist, then start (6.25 KB)
    __shared__ int gbase[NBINS];                 // 6.25 KB
    __shared__ int ts[512];                      // 2 KB

    int t = threadIdx.x;
    int base = blockIdx.x * CHUNK;
    int cnt = N_EDGES - base; if (cnt > CHUNK) cnt = CHUNK;

    for (int i = t; i < NBINS; i += 512) hs[i] = 0;
    __syncthreads();

    unsigned long long rec[APT];
    int rbin[APT], rank[APT];
#pragma unroll
    for (int k = 0; k < APT; ++k) {
        int j = t + k * 512;
        rbin[k] = -1;
        if (j < cnt) {
            int e = base + j;
            int r = __builtin_nontemporal_load(&ei[e]);
            int c = __builtin_nontemporal_load(&ei[N_EDGES + e]);
            float w = __builtin_nontemporal_load(&ew[e]);
            unsigned int w15 = (unsigned int)__float2int_rn(w * 32767.0f);
            int bin = r >> 6;
            unsigned int lo = (w15 << 17) | (unsigned int)c;
            unsigned int hi = (unsigned int)(r & 63) | ((unsigned int)bin << 6);
            rec[k] = ((unsigned long long)hi << 32) | lo;
            rbin[k] = bin;
            rank[k] = atomicAdd(&hs[bin], 1);   // rank doubles as placement
        }
    }
    __syncthreads();

    // exclusive scan over 1563 bins: 4 bins/thread + 512-wide Hillis-Steele
    int h[BPT]; int local = 0;
#pragma unroll
    for (int q = 0; q < BPT; ++q) {
        int idx = t * BPT + q;
        h[q] = (idx < NBINS) ? hs[idx] : 0;
        local += h[q];
    }
    ts[t] = local;
    __syncthreads();
    for (int off = 1; off < 512; off <<= 1) {
        int v = (t >= off) ? ts[t - off] : 0;
        __syncthreads();
        ts[t] += v;
        __syncthreads();
    }
    int run = ts[t] - local;
#pragma unroll
    for (int q = 0; q < BPT; ++q) {
        int idx = t * BPT + q;
        if (idx < NBINS) {
            hs[idx] = run;                       // hs now holds chunk-local start
            gbase[idx] = (h[q] > 0) ? atomicAdd(&bin_cursor[idx * CSTRIDE], h[q]) : 0;
            run += h[q];
        }
    }
    __syncthreads();

    // place into LDS bin-sorted using rank (no second atomic)
#pragma unroll
    for (int k = 0; k < APT; ++k)
        if (rbin[k] >= 0)
            recs[hs[rbin[k]] + rank[k]] = rec[k];
    __syncthreads();

    // coalesced copy-out into split streams
    for (int j = t; j < cnt; j += 512) {
        unsigned long long r = recs[j];
        unsigned int hi = (unsigned int)(r >> 32);
        int bin = (int)(hi >> 6);
        int gpos = gbase[bin] + (j - hs[bin]);
        if (gpos < BIN_CAP) {
            size_t o = (size_t)bin * BIN_CAP + gpos;
            pay_g[o] = (unsigned int)r;
            lrow_g[o] = (unsigned char)(hi & 63u);
        }
    }
}

// ---- fused dinv + XW: one block per 64-row bin ---------------------------
// phase 1: wsum over bin records (LDS int atomics) -> dinv (LDS + global)
// phase 2: y' = dinv .* (X W^T) for the same 64 nodes, stored bf16
__global__ __launch_bounds__(256) void dxw_k(const int* __restrict__ bin_cursor,
                                             const unsigned int* __restrict__ pay_g,
                                             const unsigned char* __restrict__ lrow_g,
                                             const float* __restrict__ x,
                                             const float* __restrict__ W,
                                             float* __restrict__ dinv,
                                             unsigned short* __restrict__ yp) {
    __shared__ float xsT[64][68];   // [k][node] 17.4 KB
    __shared__ float Wt[64][68];    // [k][feat] 17.4 KB
    __shared__ unsigned int wsumL[BIN_ROWS];
    __shared__ float dl[BIN_ROWS];
    int b = blockIdx.x, tid = threadIdx.x;
    int cnt = bin_cursor[b * CSTRIDE]; if (cnt > BIN_CAP) cnt = BIN_CAP;
    const unsigned int* pp = pay_g + (size_t)b * BIN_CAP;
    const unsigned char* lp = lrow_g + (size_t)b * BIN_CAP;

    if (tid < BIN_ROWS) wsumL[tid] = 0u;
    __syncthreads();
    for (int j = tid; j < cnt; j += 256)
        atomicAdd(&wsumL[lp[j]], pp[j] >> 17);
    __syncthreads();
    if (tid < BIN_ROWS) {
        int n = b * BIN_ROWS + tid;
        float dv = rsqrtf(1.0f + (float)wsumL[tid] * (1.0f / 32767.0f));
        dl[tid] = dv;
        if (n < N_NODES) dinv[n] = dv;
    }
    // dl visibility for the epilogue is ordered by the post-staging barrier

    int nbase = b * 64;
#pragma unroll
    for (int r = 0; r < 4; ++r) {   // W: [j][k] row-major, 4096 floats
        int idx = r * 1024 + tid * 4;
        int j = idx >> 6, k = idx & 63;
        float4 v = *(const float4*)(W + idx);
        Wt[k + 0][j] = v.x; Wt[k + 1][j] = v.y; Wt[k + 2][j] = v.z; Wt[k + 3][j] = v.w;
    }
#pragma unroll
    for (int r = 0; r < 4; ++r) {   // x block, transposed into LDS
        int idx = r * 1024 + tid * 4;
        int nl = idx >> 6, k = idx & 63;
        int n = nbase + nl;
        float4 v = (n < N_NODES) ? *(const float4*)(x + n * 64 + k)
                                 : make_float4(0.f, 0.f, 0.f, 0.f);
        xsT[k + 0][nl] = v.x; xsT[k + 1][nl] = v.y; xsT[k + 2][nl] = v.z; xsT[k + 3][nl] = v.w;
    }
    __syncthreads();

    int tx = tid & 15;          // feature group: j0 = tx*4
    int ty = tid >> 4;          // node group:    n0 = ty*4
    float acc[4][4];
#pragma unroll
    for (int i = 0; i < 4; ++i)
#pragma unroll
        for (int j = 0; j < 4; ++j) acc[i][j] = 0.f;

#pragma unroll 8
    for (int k = 0; k < 64; ++k) {
        float4 a = *(const float4*)&xsT[k][ty * 4];
        float4 w = *(const float4*)&Wt[k][tx * 4];
        float av[4] = {a.x, a.y, a.z, a.w};
        float wv[4] = {w.x, w.y, w.z, w.w};
#pragma unroll
        for (int i = 0; i < 4; ++i)
#pragma unroll
            for (int j = 0; j < 4; ++j) acc[i][j] += av[i] * wv[j];
    }
#pragma unroll
    for (int i = 0; i < 4; ++i) {
        int nl = ty * 4 + i;
        int n = nbase + nl;
        if (n < N_NODES) {
            float di = dl[nl];
            ushort4 v;
            v.x = f2bf(di * acc[i][0]);
            v.y = f2bf(di * acc[i][1]);
            v.z = f2bf(di * acc[i][2]);
            v.w = f2bf(di * acc[i][3]);
            *(ushort4*)(yp + n * 64 + tx * 4) = v;   // 8B store
        }
    }
}

// ---- pass C: LDS row-sort + fused register gather; 512 thr, 8 waves ------
// 13.5 KB LDS -> grid-limited occupancy (~24-32 waves/CU vs 12 before).
__global__ __launch_bounds__(512) void passC_k(const int* __restrict__ bin_cursor,
                                               const unsigned int* __restrict__ pay_g,
                                               const unsigned char* __restrict__ lrow_g,
                                               const float* __restrict__ dinv,
                                               const unsigned short* __restrict__ yp,
                                               const float* __restrict__ bias,
                                               float* __restrict__ out) {
    __shared__ unsigned int payL[BIN_CAP];      // 5.6 KB
    __shared__ unsigned char lrL[BIN_CAP];      // 1.4 KB
    __shared__ unsigned int outb[BIN_CAP];      // 5.6 KB
    __shared__ int hist[BIN_ROWS], rcur[BIN_ROWS], rstart[BIN_ROWS];
    __shared__ int ts[BIN_ROWS];
    __shared__ float dl[BIN_ROWS];

    int bN = blockIdx.x;
    int t = threadIdx.x;
    int cnt = bin_cursor[bN * CSTRIDE]; if (cnt > BIN_CAP) cnt = BIN_CAP;
    const unsigned int* pp = pay_g + (size_t)bN * BIN_CAP;
    const unsigned char* lp = lrow_g + (size_t)bN * BIN_CAP;

    if (t < BIN_ROWS) {
        hist[t] = 0;
        dl[t] = dinv[bN * BIN_ROWS + t];   // within 400KB alloc even past N_NODES
    }
    __syncthreads();

    // stage records in LDS + row histogram (int LDS atomics: cheap)
    for (int j = t; j < cnt; j += 512) {
        unsigned int p = pp[j];
        unsigned char l = lp[j];
        payL[j] = p; lrL[j] = l;
        atomicAdd(&hist[l], 1);
    }
    __syncthreads();

    // exclusive scan of 64 row counts (threads 0..63)
    int own = (t < BIN_ROWS) ? hist[t] : 0;
    if (t < BIN_ROWS) ts[t] = own;
    __syncthreads();
    for (int off = 1; off < BIN_ROWS; off <<= 1) {
        int v = (t >= off && t < BIN_ROWS) ? ts[t - off] : 0;
        __syncthreads();
        if (t < BIN_ROWS) ts[t] += v;
        __syncthreads();
    }
    if (t < BIN_ROWS) {
        int rs = ts[t] - own;
        rcur[t] = rs;
        rstart[t] = rs;
    }
    __syncthreads();

    // reorder row-sorted within LDS (4B records)
    for (int j = t; j < cnt; j += 512) {
        int p = atomicAdd(&rcur[lrL[j]], 1);
        outb[p] = payL[j];
    }
    __syncthreads();

    // fused gather: wave wv owns rows [wv*8, wv*8+8); register acc.
    int wv = t >> 6, lane = t & 63;
    float bl = bias[lane];
    for (int lr = wv * 8; lr < wv * 8 + 8; ++lr) {
        int n = bN * BIN_ROWS + lr;
        if (n >= N_NODES) break;
        int rs = rstart[lr];
        int re = rs + hist[lr];
        float self = bf2f(yp[n * D + lane]);
        float a0 = 0.f, a1 = 0.f;
        // 16-deep batches; sentinel-pad short batches (col=n, w15=0 -> no-op)
        for (int j = rs; j < re; j += 16) {
            unsigned int u[16];
#pragma unroll
            for (int q = 0; q < 16; ++q)
                u[q] = (j + q < re) ? outb[j + q] : (unsigned int)n;
            float yv[16];
#pragma unroll
            for (int q = 0; q < 16; ++q)
                yv[q] = bf2f(yp[(u[q] & 0x1FFFFu) * D + lane]);
#pragma unroll
            for (int q = 0; q < 16; ++q) {
                float wf = (float)(u[q] >> 17);
                if (q & 1) a1 += wf * yv[q];
                else       a0 += wf * yv[q];
            }
        }
        float o = dl[lr] * (self + (a0 + a1) * (1.0f / 32767.0f)) + bl;
        __builtin_nontemporal_store(o, &out[n * D + lane]);
    }
}

// ---------------------------------------------------------------------------
extern "C" void kernel_launch(void* const* d_in, const int* in_sizes, int n_in,
                              void* d_out, int out_size, void* d_ws, size_t ws_size,
                              hipStream_t stream) {
    const float* x  = (const float*)d_in[0];
    const int*   ei = (const int*)d_in[1];     // [2, E]
    const float* ew = (const float*)d_in[2];
    const float* W  = (const float*)d_in[3];
    const float* b  = (const float*)d_in[4];
    float* out = (float*)d_out;

    char* ws = (char*)d_ws;
    int*            bin_cursor = (int*)            ws;                 // 100 KB (padded)
    float*          dinv       = (float*)         (ws + 0x20000);      // 400 KB
    unsigned short* yp         = (unsigned short*)(ws + 0x90000);      // 12.8 MB
    unsigned int*   pay_g      = (unsigned int*)  (ws + 0xD10000);     // 8.8 MB
    unsigned char*  lrow_g     = (unsigned char*) (ws + 0x1610000);    // 2.2 MB (end ~24.5 MB)

    hipMemsetAsync(bin_cursor, 0, NBINS * CSTRIDE * sizeof(int), stream);
    passA_k<<<NCHUNK, 512, 0, stream>>>(ei, ew, bin_cursor, pay_g, lrow_g);
    dxw_k  <<<NBINS, 256, 0, stream>>>(bin_cursor, pay_g, lrow_g, x, W, dinv, yp);
    passC_k<<<NBINS, 512, 0, stream>>>(bin_cursor, pay_g, lrow_g, dinv, yp, b, out);
}

// Round 8
// 194.169 us; speedup vs baseline: 4.1878x; 1.0181x over previous
//
#include <hip/hip_runtime.h>

#define N_NODES 100000
#define N_EDGES 1600000
#define D 64

#define BIN_ROWS 64        // rows per bin
#define NBINS 1563         // ceil(100000 / 64)
#define NB1 (NBINS + 1)
#define BIN_CAP 1408       // mean 1024, sigma ~32 -> +12 sigma
#define CHUNK 4096         // edges per pass-A block
#define NCHUNK ((N_EDGES + CHUNK - 1) / CHUNK)   // 391
#define APT (CHUNK / 512)  // 8 edges per thread in passA
#define BPT 4              // bins per thread in passA scan (512*4 >= 1563)

__device__ __forceinline__ unsigned short f2bf(float f) {   // RNE float->bf16
    unsigned int u = __float_as_uint(f);
    u += 0x7FFFu + ((u >> 16) & 1u);
    return (unsigned short)(u >> 16);
}
__device__ __forceinline__ float bf2f(unsigned short u) {
    return __uint_as_float(((unsigned int)u) << 16);
}

// ---- pass A: LDS multisplit -> CHUNK-CONTIGUOUS output (all writes
// coalesced and block-private; no global atomics, no memset).
// chunkbuf record u64: lo32 = (w15<<17)|col ; hi32 = lrow(6b) | (bin<<6)
// starts_g[chunk][bin] = chunk-local exclusive start of bin's run;
// starts_g[chunk][NBINS] = chunk edge count (so len = next - cur).
__global__ __launch_bounds__(512) void passA_k(const int* __restrict__ ei,
                                               const float* __restrict__ ew,
                                               int* __restrict__ starts_g,
                                               unsigned long long* __restrict__ chunkbuf) {
    __shared__ unsigned long long recs[CHUNK];   // 32 KB
    __shared__ int hs[NBINS];                    // hist, then start (6.25 KB)
    __shared__ int ts[512];                      // 2 KB

    int t = threadIdx.x;
    int base = blockIdx.x * CHUNK;
    int cnt = N_EDGES - base; if (cnt > CHUNK) cnt = CHUNK;

    for (int i = t; i < NBINS; i += 512) hs[i] = 0;
    __syncthreads();

    unsigned long long rec[APT];
    int rbin[APT], rank[APT];
#pragma unroll
    for (int k = 0; k < APT; ++k) {
        int j = t + k * 512;
        rbin[k] = -1;
        if (j < cnt) {
            int e = base + j;
            int r = __builtin_nontemporal_load(&ei[e]);
            int c = __builtin_nontemporal_load(&ei[N_EDGES + e]);
            float w = __builtin_nontemporal_load(&ew[e]);
            unsigned int w15 = (unsigned int)__float2int_rn(w * 32767.0f);
            int bin = r >> 6;
            unsigned int lo = (w15 << 17) | (unsigned int)c;
            unsigned int hi = (unsigned int)(r & 63) | ((unsigned int)bin << 6);
            rec[k] = ((unsigned long long)hi << 32) | lo;
            rbin[k] = bin;
            rank[k] = atomicAdd(&hs[bin], 1);   // rank doubles as placement
        }
    }
    __syncthreads();

    // exclusive scan over 1563 bins: 4 bins/thread + 512-wide Hillis-Steele
    int h[BPT]; int local = 0;
#pragma unroll
    for (int q = 0; q < BPT; ++q) {
        int idx = t * BPT + q;
        h[q] = (idx < NBINS) ? hs[idx] : 0;
        local += h[q];
    }
    ts[t] = local;
    __syncthreads();
    for (int off = 1; off < 512; off <<= 1) {
        int v = (t >= off) ? ts[t - off] : 0;
        __syncthreads();
        ts[t] += v;
        __syncthreads();
    }
    int run = ts[t] - local;
#pragma unroll
    for (int q = 0; q < BPT; ++q) {
        int idx = t * BPT + q;
        if (idx < NBINS) {
            hs[idx] = run;                               // chunk-local start
            starts_g[blockIdx.x * NB1 + idx] = run;      // coalesced write
            run += h[q];
        }
    }
    if (t == 0) starts_g[blockIdx.x * NB1 + NBINS] = cnt;
    __syncthreads();

    // place into LDS bin-sorted using rank (no second atomic)
#pragma unroll
    for (int k = 0; k < APT; ++k)
        if (rbin[k] >= 0)
            recs[hs[rbin[k]] + rank[k]] = rec[k];
    __syncthreads();

    // PERFECTLY coalesced, block-private copy-out
    for (int j = t; j < cnt; j += 512)
        chunkbuf[(size_t)blockIdx.x * CHUNK + j] = recs[j];
}

// ---- compact: per 64-row bin, gather 391 fragments (scattered READS,
// L2/L3-served), row-sort in LDS, emit dinv + bin-contiguous CSR ---------
__global__ __launch_bounds__(512) void compact_k(const int* __restrict__ starts_g,
                                                 const unsigned long long* __restrict__ chunkbuf,
                                                 unsigned int* __restrict__ csr,
                                                 int* __restrict__ row_start,
                                                 int* __restrict__ row_cnt,
                                                 float* __restrict__ dinv) {
    __shared__ unsigned long long stage[BIN_CAP];   // 11.3 KB
    __shared__ unsigned int outb[BIN_CAP];          // 5.6 KB
    __shared__ int fstart[NCHUNK], flen[NCHUNK];    // 3.1 KB
    __shared__ int ts[512];                         // 2 KB
    __shared__ int hist[BIN_ROWS], rcur[BIN_ROWS], rsl[BIN_ROWS];
    __shared__ unsigned int wsum[BIN_ROWS];

    int b = blockIdx.x, t = threadIdx.x;

    if (t < NCHUNK) {
        int s = starts_g[t * NB1 + b];
        int e = starts_g[t * NB1 + b + 1];   // adjacent int: same line
        fstart[t] = s; flen[t] = e - s;
    }
    if (t < BIN_ROWS) { hist[t] = 0; wsum[t] = 0u; }
    __syncthreads();

    // exclusive scan of 391 fragment lengths -> LDS placement offsets
    int own = (t < NCHUNK) ? flen[t] : 0;
    ts[t] = own;
    __syncthreads();
    for (int off = 1; off < 512; off <<= 1) {
        int v = (t >= off) ? ts[t - off] : 0;
        __syncthreads();
        ts[t] += v;
        __syncthreads();
    }
    int loff = ts[t] - own;
    int cnt = ts[511];                  // total records in this bin
    if (cnt > BIN_CAP) cnt = BIN_CAP;   // statistically unreachable guard

    // fragment gather: thread t copies chunk t's run (mean 2.6 records)
    if (t < NCHUNK) {
        const unsigned long long* src = chunkbuf + (size_t)t * CHUNK + fstart[t];
        int L = flen[t];
        for (int i = 0; i < L; ++i) {
            int p = loff + i;
            if (p < BIN_CAP) stage[p] = src[i];
        }
    }
    __syncthreads();

    // row histogram + weight sums (int LDS atomics: proven cheap)
    for (int j = t; j < cnt; j += 512) {
        unsigned long long r = stage[j];
        unsigned int hi = (unsigned int)(r >> 32);
        atomicAdd(&hist[hi & 63u], 1);
        atomicAdd(&wsum[hi & 63u], ((unsigned int)r) >> 17);
    }
    __syncthreads();

    // exclusive scan of 64 row counts
    if (t < BIN_ROWS) ts[t] = hist[t];
    __syncthreads();
    for (int off = 1; off < BIN_ROWS; off <<= 1) {
        int v = (t >= off && t < BIN_ROWS) ? ts[t - off] : 0;
        __syncthreads();
        if (t < BIN_ROWS) ts[t] += v;
        __syncthreads();
    }
    if (t < BIN_ROWS) {
        int rs = ts[t] - hist[t];
        rcur[t] = rs; rsl[t] = rs;
        int n = b * BIN_ROWS + t;
        if (n < N_NODES) {
            row_start[n] = b * BIN_CAP + rs;
            row_cnt[n] = hist[t];
            dinv[n] = rsqrtf(1.0f + (float)wsum[t] * (1.0f / 32767.0f));
        }
    }
    __syncthreads();

    // row-sort within LDS (4B records)
    for (int j = t; j < cnt; j += 512) {
        unsigned long long r = stage[j];
        int p = atomicAdd(&rcur[(unsigned int)(r >> 32) & 63u], 1);
        outb[p] = (unsigned int)r;      // (w15<<17)|col
    }
    __syncthreads();

    // coalesced, block-private copy-out
    for (int j = t; j < cnt; j += 512)
        csr[(size_t)b * BIN_CAP + j] = outb[j];
}

// ---------------------- y' = dinv .* (X * W^T), stored bf16 ---------------
__global__ __launch_bounds__(256) void xw_k(const float* __restrict__ x,
                                            const float* __restrict__ W,
                                            const float* __restrict__ dinv,
                                            unsigned short* __restrict__ yp) {
    __shared__ float xsT[64][68];   // [k][node]
    __shared__ float Wt[64][68];    // [k][feat]
    int tid = threadIdx.x;
    int nbase = blockIdx.x * 64;
#pragma unroll
    for (int r = 0; r < 4; ++r) {   // W: [j][k] row-major, 4096 floats
        int idx = r * 1024 + tid * 4;
        int j = idx >> 6, k = idx & 63;
        float4 v = *(const float4*)(W + idx);
        Wt[k + 0][j] = v.x; Wt[k + 1][j] = v.y; Wt[k + 2][j] = v.z; Wt[k + 3][j] = v.w;
    }
#pragma unroll
    for (int r = 0; r < 4; ++r) {   // x block, transposed into LDS
        int idx = r * 1024 + tid * 4;
        int nl = idx >> 6, k = idx & 63;
        int n = nbase + nl;
        float4 v = (n < N_NODES) ? *(const float4*)(x + n * 64 + k)
                                 : make_float4(0.f, 0.f, 0.f, 0.f);
        xsT[k + 0][nl] = v.x; xsT[k + 1][nl] = v.y; xsT[k + 2][nl] = v.z; xsT[k + 3][nl] = v.w;
    }
    __syncthreads();

    int tx = tid & 15;          // feature group: j0 = tx*4
    int ty = tid >> 4;          // node group:    n0 = ty*4
    float acc[4][4];
#pragma unroll
    for (int i = 0; i < 4; ++i)
#pragma unroll
        for (int j = 0; j < 4; ++j) acc[i][j] = 0.f;

#pragma unroll 8
    for (int k = 0; k < 64; ++k) {
        float4 a = *(const float4*)&xsT[k][ty * 4];
        float4 w = *(const float4*)&Wt[k][tx * 4];
        float av[4] = {a.x, a.y, a.z, a.w};
        float wv[4] = {w.x, w.y, w.z, w.w};
#pragma unroll
        for (int i = 0; i < 4; ++i)
#pragma unroll
            for (int j = 0; j < 4; ++j) acc[i][j] += av[i] * wv[j];
    }
#pragma unroll
    for (int i = 0; i < 4; ++i) {
        int n = nbase + ty * 4 + i;
        if (n < N_NODES) {
            float di = dinv[n];
            ushort4 v;
            v.x = f2bf(di * acc[i][0]);
            v.y = f2bf(di * acc[i][1]);
            v.z = f2bf(di * acc[i][2]);
            v.w = f2bf(di * acc[i][3]);
            *(ushort4*)(yp + n * 64 + tx * 4) = v;   // 8B store
        }
    }
}

// ---- gather: 1 wave per row; wave-cooperative CSR fetch + readlane --------
// (round-0/1-proven 53us kernel; row extents from row_start/row_cnt)
__global__ __launch_bounds__(256) void gather_k(const int* __restrict__ row_start,
                                                const int* __restrict__ row_cnt,
                                                const float* __restrict__ dinv,
                                                const unsigned int* __restrict__ csr,
                                                const unsigned short* __restrict__ yp,
                                                const float* __restrict__ b,
                                                float* __restrict__ out) {
    int wv = threadIdx.x >> 6;
    int lane = threadIdx.x & 63;
    int n = blockIdx.x * 4 + wv;          // grid covers exactly 100000

    int s = row_start[n];
    int cnt = row_cnt[n];
    float self = bf2f(yp[n * D + lane]);  // self-loop term
    float acc0 = 0.f, acc1 = 0.f;         // dual accumulators: break FMA chain

    for (int base = 0; base < cnt; base += 64) {
        int m = cnt - base; if (m > 64) m = 64;
        unsigned int rec = (lane < m) ? csr[s + base + lane] : 0u;
        int r = 0;
        for (; r + 7 < m; r += 8) {
            unsigned int u[8];
#pragma unroll
            for (int q = 0; q < 8; ++q)
                u[q] = __builtin_amdgcn_readlane(rec, r + q);
            float yv[8];
#pragma unroll
            for (int q = 0; q < 8; ++q)
                yv[q] = bf2f(yp[(u[q] & 0x1FFFFu) * D + lane]);
#pragma unroll
            for (int q = 0; q < 8; ++q) {
                float wf = (float)(u[q] >> 17);
                if (q & 1) acc1 += wf * yv[q];
                else       acc0 += wf * yv[q];
            }
        }
        for (; r < m; ++r) {
            unsigned int u = __builtin_amdgcn_readlane(rec, r);
            acc0 += (float)(u >> 17) * bf2f(yp[(u & 0x1FFFFu) * D + lane]);
        }
    }

    float o = dinv[n] * (self + (acc0 + acc1) * (1.0f / 32767.0f)) + b[lane];
    __builtin_nontemporal_store(o, &out[n * D + lane]);
}

// ---------------------------------------------------------------------------
extern "C" void kernel_launch(void* const* d_in, const int* in_sizes, int n_in,
                              void* d_out, int out_size, void* d_ws, size_t ws_size,
                              hipStream_t stream) {
    const float* x  = (const float*)d_in[0];
    const int*   ei = (const int*)d_in[1];     // [2, E]
    const float* ew = (const float*)d_in[2];
    const float* W  = (const float*)d_in[3];
    const float* b  = (const float*)d_in[4];
    float* out = (float*)d_out;

    char* ws = (char*)d_ws;
    // chunkbuf (12.8MB) is dead after compact_k; yp overlays it (12.8MB).
    unsigned long long* chunkbuf  = (unsigned long long*) ws;
    unsigned short*     yp        = (unsigned short*)     ws;
    int*                starts_g  = (int*)          (ws + 0xD00000);   // 2.45 MB
    unsigned int*       csr       = (unsigned int*) (ws + 0x1000000);  // 8.8 MB
    int*                row_start = (int*)          (ws + 0x1900000);  // 400 KB
    int*                row_cnt   = (int*)          (ws + 0x1980000);  // 400 KB
    float*              dinv      = (float*)        (ws + 0x1A00000);  // 400 KB (end ~27.7MB)

    passA_k  <<<NCHUNK, 512, 0, stream>>>(ei, ew, starts_g, chunkbuf);
    compact_k<<<NBINS, 512, 0, stream>>>(starts_g, chunkbuf, csr, row_start, row_cnt, dinv);
    xw_k     <<<(N_NODES + 63) / 64, 256, 0, stream>>>(x, W, dinv, yp);
    gather_k <<<N_NODES / 4, 256, 0, stream>>>(row_start, row_cnt, dinv, csr, yp, b, out);
}